// Round 1
// baseline (21643.567 us; speedup 1.0000x reference)
//
#include <hip/hip_runtime.h>
#include <hip/hip_cooperative_groups.h>

namespace cg = cooperative_groups;

typedef short bf16x8 __attribute__((ext_vector_type(8)));
typedef float f32x4 __attribute__((ext_vector_type(4)));

__device__ __forceinline__ unsigned short f2bf(float f) {
  unsigned u = __float_as_uint(f);
  unsigned r = (u + 0x7FFFu + ((u >> 16) & 1u)) >> 16;
  return (unsigned short)r;
}
__device__ __forceinline__ float bf2f(unsigned short s) {
  return __uint_as_float(((unsigned)s) << 16);
}
__device__ __forceinline__ float sigm(float x) {
  return __builtin_amdgcn_rcpf(1.f + __expf(-x));
}
__device__ __forceinline__ float tanh_a(float x) {
  return 1.f - 2.f * __builtin_amdgcn_rcpf(__expf(2.f * x) + 1.f);
}

__device__ __forceinline__ void gload_lds16(const void* g, void* l) {
  __builtin_amdgcn_global_load_lds(
      (const __attribute__((address_space(1))) unsigned int*)g,
      (__attribute__((address_space(3))) unsigned int*)l, 16, 0, 0);
}

// ---------------- pack kernels ----------------

__global__ void k_cvt_x(const float* __restrict__ x, unsigned short* __restrict__ xb, int n4) {
  int i = blockIdx.x * blockDim.x + threadIdx.x;
  if (i < n4) {
    float4 v = ((const float4*)x)[i];
    ushort4 o;
    o.x = f2bf(v.x); o.y = f2bf(v.y); o.z = f2bf(v.z); o.w = f2bf(v.w);
    ((ushort4*)xb)[i] = o;
  }
}

// transpose 1024x1024 fp32 -> bf16, 8 slabs (4 wx gates -> wxt, 4 wh gates -> whp)
__global__ void k_pack_w(const float* __restrict__ wxi, const float* __restrict__ wxf,
                         const float* __restrict__ wxg, const float* __restrict__ wxo,
                         const float* __restrict__ whi, const float* __restrict__ whf,
                         const float* __restrict__ whg, const float* __restrict__ who,
                         unsigned short* __restrict__ wxt, unsigned short* __restrict__ whp) {
  const float* srcs[8] = {wxi, wxf, wxg, wxo, whi, whf, whg, who};
  int slab = blockIdx.z;
  const float* src = srcs[slab];
  int gate = slab & 3;
  bool is_wh = slab >= 4;
  __shared__ float tile[32][33];
  int tx = threadIdx.x, ty = threadIdx.y;
  int j0 = blockIdx.x * 32, k0 = blockIdx.y * 32;
  #pragma unroll
  for (int i = 0; i < 32; i += 8)
    tile[ty + i][tx] = src[(size_t)(k0 + ty + i) * 1024 + j0 + tx];
  __syncthreads();
  unsigned short* dst = is_wh ? whp : wxt;
  #pragma unroll
  for (int i = 0; i < 32; i += 8) {
    int j = j0 + ty + i;
    int k = k0 + tx;
    float v = tile[tx][ty + i];
    int row = is_wh ? ((j >> 2) * 16 + gate * 4 + (j & 3)) : (gate * 1024 + j);
    dst[(size_t)row * 1024 + k] = f2bf(v);
  }
}

__global__ void k_bias(const float* bxi, const float* bhi, const float* bxf, const float* bhf,
                       const float* bxg, const float* bhg, const float* bxo, const float* bho,
                       float* __restrict__ bx4) {
  int n = blockIdx.x * 256 + threadIdx.x;  // 0..4095
  int gate = n >> 10, j = n & 1023;
  const float* a = gate == 0 ? bxi : gate == 1 ? bxf : gate == 2 ? bxg : bxo;
  const float* b = gate == 0 ? bhi : gate == 1 ? bhf : gate == 2 ? bhg : bho;
  bx4[n] = a[j] + b[j];
}

// ---------------- xproj GEMM: (32768x1024) @ (1024x4096) -> bf16 ----------------
// 128x128 tile, BK=64, global_load_lds w=16, XOR-swizzled LDS.

__global__ __launch_bounds__(256) void k_xproj(
    const unsigned short* __restrict__ xb,   // [32768][1024] bf16
    const unsigned short* __restrict__ wxt,  // [4096][1024]  bf16 (B^T)
    const float* __restrict__ bx4,           // [4096]
    unsigned short* __restrict__ xp)         // [32768][4096] bf16
{
  __shared__ __align__(16) short As[128 * 64];
  __shared__ __align__(16) short Bs[128 * 64];
  const int tid = threadIdx.x;
  const int bid = blockIdx.x;
  const int m0 = (bid >> 5) * 128;
  const int n0 = (bid & 31) * 128;
  const int lane = tid & 63, w = tid >> 6;
  const int l15 = lane & 15, hi = lane >> 4;
  const int mrow0 = (w >> 1) * 64, ncol0 = (w & 1) * 64;

  f32x4 acc[4][4] = {};
  const char* xbB = (const char*)xb;
  const char* wtB = (const char*)wxt;

  for (int ks = 0; ks < 16; ++ks) {
    #pragma unroll
    for (int c = 0; c < 4; ++c) {
      int d = c * 4096 + tid * 16;
      int r = d >> 7;
      int kb = (d & 127) ^ ((r & 7) << 4);
      gload_lds16(xbB + ((size_t)(m0 + r) * 2048 + ks * 128 + kb), (char*)As + d);
    }
    #pragma unroll
    for (int c = 0; c < 4; ++c) {
      int d = c * 4096 + tid * 16;
      int r = d >> 7;
      int kb = (d & 127) ^ ((r & 7) << 4);
      gload_lds16(wtB + ((size_t)(n0 + r) * 2048 + ks * 128 + kb), (char*)Bs + d);
    }
    __syncthreads();
    #pragma unroll
    for (int kk = 0; kk < 2; ++kk) {
      bf16x8 a[4], b[4];
      #pragma unroll
      for (int mt = 0; mt < 4; ++mt) {
        int r = mrow0 + mt * 16 + l15;
        int byt = r * 128 + ((kk * 64 + hi * 16) ^ ((r & 7) << 4));
        a[mt] = *(const bf16x8*)((const char*)As + byt);
      }
      #pragma unroll
      for (int nt = 0; nt < 4; ++nt) {
        int r = ncol0 + nt * 16 + l15;
        int byt = r * 128 + ((kk * 64 + hi * 16) ^ ((r & 7) << 4));
        b[nt] = *(const bf16x8*)((const char*)Bs + byt);
      }
      #pragma unroll
      for (int mt = 0; mt < 4; ++mt)
        #pragma unroll
        for (int nt = 0; nt < 4; ++nt)
          acc[mt][nt] = __builtin_amdgcn_mfma_f32_16x16x32_bf16(a[mt], b[nt], acc[mt][nt], 0, 0, 0);
    }
    __syncthreads();
  }
  float bias[4];
  #pragma unroll
  for (int nt = 0; nt < 4; ++nt) bias[nt] = bx4[n0 + ncol0 + nt * 16 + l15];
  #pragma unroll
  for (int mt = 0; mt < 4; ++mt)
    #pragma unroll
    for (int nt = 0; nt < 4; ++nt) {
      int col = n0 + ncol0 + nt * 16 + l15;
      #pragma unroll
      for (int ri = 0; ri < 4; ++ri) {
        int row = m0 + mrow0 + mt * 16 + hi * 4 + ri;
        xp[(size_t)row * 4096 + col] = f2bf(acc[mt][nt][ri] + bias[nt]);
      }
    }
}

// ---------------- persistent recurrence: 512 steps, 1 grid.sync per step ----------------
// 256 blocks (1/CU); block g owns h-cols [4g, 4g+4). Wave w owns batch rows [16w, 16w+16).
// GEMM per wave: 16x16 output (16 gate cols = 4 gates x 4 j), K=1024 -> 32 MFMA.

__global__ __launch_bounds__(256, 1) void k_lstm(
    const unsigned short* __restrict__ whp,  // [256*16][1024] bf16 packed
    const unsigned short* __restrict__ xp,   // [32768][4096] bf16 (biases folded)
    unsigned short* __restrict__ hbuf,       // [2][64][1024] bf16
    float* __restrict__ out)                 // h (65536) then c (65536), fp32
{
  const int g = blockIdx.x;
  const int j0 = g * 4;
  const int tid = threadIdx.x;
  const int lane = tid & 63, w = tid >> 6;
  const int l15 = lane & 15, hi = lane >> 4;
  const int gate = l15 >> 2, jj = l15 & 3;

  const unsigned short* wrow = whp + (size_t)(g * 16 + l15) * 1024 + hi * 8;
  float cst[4] = {0.f, 0.f, 0.f, 0.f};

  cg::grid_group grid = cg::this_grid();

  for (int t = 0; t < 512; ++t) {
    const unsigned short* hc = hbuf + (t & 1) * 65536;
    const unsigned short* arow = hc + (16 * w + l15) * 1024 + hi * 8;
    f32x4 acc = {0.f, 0.f, 0.f, 0.f};
    #pragma unroll 8
    for (int ks = 0; ks < 32; ++ks) {
      bf16x8 a = *(const bf16x8*)(arow + ks * 32);
      bf16x8 b = *(const bf16x8*)(wrow + ks * 32);
      acc = __builtin_amdgcn_mfma_f32_16x16x32_bf16(a, b, acc, 0, 0, 0);
    }
    const int n = gate * 1024 + j0 + jj;
    float act[4];
    #pragma unroll
    for (int ri = 0; ri < 4; ++ri) {
      int b = 16 * w + hi * 4 + ri;
      float v = acc[ri] + bf2f(xp[((size_t)b * 512 + t) * 4096 + n]);
      act[ri] = (gate == 2) ? tanh_a(v) : sigm(v);
    }
    const int base = (lane & 48) | jj;
    float hv[4];
    #pragma unroll
    for (int ri = 0; ri < 4; ++ri) {
      float iv = __shfl(act[ri], base);
      float fv = __shfl(act[ri], base + 4);
      float gv = __shfl(act[ri], base + 8);
      float ov = __shfl(act[ri], base + 12);
      cst[ri] = fv * cst[ri] + iv * gv;
      hv[ri] = ov * tanh_a(cst[ri]);
    }
    unsigned short* hn = hbuf + ((t + 1) & 1) * 65536;
    if (gate == 0) {
      #pragma unroll
      for (int ri = 0; ri < 4; ++ri) {
        int b = 16 * w + hi * 4 + ri;
        hn[b * 1024 + j0 + jj] = f2bf(hv[ri]);
      }
      if (t == 511) {
        #pragma unroll
        for (int ri = 0; ri < 4; ++ri) {
          int b = 16 * w + hi * 4 + ri;
          out[b * 1024 + j0 + jj] = hv[ri];
          out[65536 + b * 1024 + j0 + jj] = cst[ri];
        }
      }
    }
    grid.sync();
  }
}

// ---------------- host ----------------

extern "C" void kernel_launch(void* const* d_in, const int* in_sizes, int n_in,
                              void* d_out, int out_size, void* d_ws, size_t ws_size,
                              hipStream_t stream) {
  const float* x = (const float*)d_in[0];
  // setup_inputs order: x, wxi, whi, wxf, whf, wxg, whg, wxo, who, bxi,bhi,bxf,bhf,bxg,bhg,bxo,bho
  const float* wxi = (const float*)d_in[1];
  const float* whi = (const float*)d_in[2];
  const float* wxf = (const float*)d_in[3];
  const float* whf = (const float*)d_in[4];
  const float* wxg = (const float*)d_in[5];
  const float* whg = (const float*)d_in[6];
  const float* wxo = (const float*)d_in[7];
  const float* who = (const float*)d_in[8];

  char* ws = (char*)d_ws;
  unsigned short* xb   = (unsigned short*)(ws);                    // 64 MiB
  unsigned short* wxt  = (unsigned short*)(ws + 67108864);         // 8 MiB
  unsigned short* whp  = (unsigned short*)(ws + 75497472);         // 8 MiB
  unsigned short* xpj  = (unsigned short*)(ws + 83886080);         // 256 MiB
  float*          bx4  = (float*)(ws + 352321536);                 // 16 KiB
  unsigned short* hbuf = (unsigned short*)(ws + 352337920);        // 256 KiB

  k_cvt_x<<<32768, 256, 0, stream>>>(x, xb, 8388608);
  k_pack_w<<<dim3(32, 32, 8), dim3(32, 8), 0, stream>>>(wxi, wxf, wxg, wxo, whi, whf, whg, who, wxt, whp);
  k_bias<<<16, 256, 0, stream>>>((const float*)d_in[9], (const float*)d_in[10],
                                 (const float*)d_in[11], (const float*)d_in[12],
                                 (const float*)d_in[13], (const float*)d_in[14],
                                 (const float*)d_in[15], (const float*)d_in[16], bx4);
  hipMemsetAsync(hbuf, 0, 262144, stream);
  k_xproj<<<8192, 256, 0, stream>>>(xb, wxt, bx4, xpj);

  float* out = (float*)d_out;
  void* args[] = {(void*)&whp, (void*)&xpj, (void*)&hbuf, (void*)&out};
  hipLaunchCooperativeKernel((const void*)k_lstm, dim3(256), dim3(256), args, 0, stream);
}